// Round 8
// baseline (270.527 us; speedup 1.0000x reference)
//
#include <hip/hip_runtime.h>

// LinearAttention (fp32 in/out, bf16 internal MFMA):
// x(8,64,64,256) f32, w_qkv(256,1536) f32, gn_scale/bias(512) f32,
// w_out(512,256) f32, b_out(256) f32 -> out(8,64,64,256) f32
// B=8, N=4096 tokens/batch, HEADS=8, DH=64, HID=512, DIM=256.
//
// Softmaxes WITHOUT max subtraction (|q|,|k| <~ 6, exp fp32-safe).
// q[token][512] token-major; k,v produced TRANSPOSED as kvT[feat][32768]
// (operand-swapped GEMM, XCD-friendly grid), k rows store exp().
// ctx partials non-atomic; reduce folds partials AND bakes kinv-scaling +
// bf16 + MFMA-swizzle into ctxB. qp: 128-token blocks, MFMA on raw exp(q),
// epilogue row-scale 0.125/s_n. GN folded into final GEMM.

typedef unsigned short ushort_t;
typedef __attribute__((ext_vector_type(8))) short short8;
typedef __attribute__((ext_vector_type(4))) float floatx4;

__device__ __forceinline__ float b2f(ushort_t u) {
  unsigned int i = ((unsigned int)u) << 16;
  float f;
  __builtin_memcpy(&f, &i, 4);
  return f;
}
__device__ __forceinline__ ushort_t f2b(float f) {
  unsigned int i;
  __builtin_memcpy(&i, &f, 4);
  unsigned int r = (i + 0x7FFFu + ((i >> 16) & 1u)) >> 16;
  return (ushort_t)r;
}

// async 16B global->LDS copy (HW dest = wave-uniform base + lane*16)
__device__ __forceinline__ void load_lds16(const ushort_t* g, ushort_t* l) {
  __builtin_amdgcn_global_load_lds(
      (const __attribute__((address_space(1))) unsigned int*)g,
      (__attribute__((address_space(3))) unsigned int*)l, 16, 0, 0);
}

// ---------------------------------------------------------------------------
__global__ __launch_bounds__(256) void cast_f32_bf16(
    const float* __restrict__ in, ushort_t* __restrict__ out) {
  long i = ((long)blockIdx.x * 256 + threadIdx.x) * 4;
  float4 v = *(const float4*)(in + i);
  ushort4 o;
  o.x = f2b(v.x);
  o.y = f2b(v.y);
  o.z = f2b(v.z);
  o.w = f2b(v.w);
  *(ushort4*)(out + i) = o;
}

// ---------------------------------------------------------------------------
__global__ __launch_bounds__(256) void transpose_f32_bf16(
    const float* __restrict__ in, ushort_t* __restrict__ out, int R, int C,
    const float* __restrict__ scale) {
  __shared__ ushort_t t[32][33];
  int c0 = blockIdx.x * 32, r0 = blockIdx.y * 32;
  int tx = threadIdx.x & 31, ty = threadIdx.x >> 5;
  for (int i = 0; i < 32; i += 8) {
    float s = scale ? scale[r0 + ty + i] : 1.0f;
    t[ty + i][tx] = f2b(in[(long)(r0 + ty + i) * C + c0 + tx] * s);
  }
  __syncthreads();
  for (int i = 0; i < 32; i += 8)
    out[(long)(c0 + ty + i) * R + r0 + tx] = t[tx][ty + i];
}

// ---------------------------------------------------------------------------
__global__ __launch_bounds__(64) void prep_gw_kernel(
    const float* __restrict__ gn_scale, const float* __restrict__ gn_bias,
    const float* __restrict__ w_out, const float* __restrict__ b_out,
    float* __restrict__ gw1, float* __restrict__ bias2) {
  int c = blockIdx.x * 64 + threadIdx.x;
  float g1 = 0.f, b2 = 0.f;
  for (int f = 0; f < 512; ++f) {
    float w = w_out[f * 256 + c];
    g1 += gn_scale[f] * w;
    b2 += gn_bias[f] * w;
  }
  gw1[c] = g1;
  bias2[c] = b2 + b_out[c];
}

// ---------------------------------------------------------------------------
// MFMA GEMM: C[M,F] = A[M,K] @ Bt[F,K]^T  (bf16 in, fp32 acc)
// MODE 0: bf16 out. MODE 1: bf16 out, rows<512 store exp(acc).
// MODE 2: fp32 out + folded GroupNorm. SWAP: blockIdx.x indexes F (tokens)
// so one x-round streams Bt once (L3-friendly when A is tiny).
// ---------------------------------------------------------------------------
template <int MODE, bool SWAP>
__global__ __launch_bounds__(256) void gemm_tpl(
    const ushort_t* __restrict__ A, const ushort_t* __restrict__ Bt,
    void* __restrict__ Cv, int M, int K, int F,
    const float* __restrict__ murs, const float* __restrict__ gw1,
    const float* __restrict__ bias2) {
  __shared__ __align__(16) ushort_t As[128][32];
  __shared__ __align__(16) ushort_t Bs[128][32];
  int tid = threadIdx.x;
  long m0 = (long)(SWAP ? blockIdx.y : blockIdx.x) * 128;
  long f0 = (long)(SWAP ? blockIdx.x : blockIdx.y) * 128;
  int wv = tid >> 6, lane = tid & 63;
  int wm = wv & 1, wf = wv >> 1;
  int l15 = lane & 15, quad = lane >> 4;

  floatx4 acc[4][4];
  floatx4 zero = {0.f, 0.f, 0.f, 0.f};
  for (int i = 0; i < 4; i++)
    for (int j = 0; j < 4; j++) acc[i][j] = zero;

  for (int k0 = 0; k0 < K; k0 += 32) {
    __syncthreads();
#pragma unroll
    for (int r = 0; r < 2; ++r) {
      int chunk = r * 256 + tid;
      int row = chunk >> 2;
      int kc = chunk & 3;
      load_lds16(A + (m0 + row) * (long)K + k0 + kc * 8, &As[row][kc * 8]);
      load_lds16(Bt + (f0 + row) * (long)K + k0 + kc * 8, &Bs[row][kc * 8]);
    }
    __syncthreads();
    short8 af[4], bfr[4];
#pragma unroll
    for (int mt = 0; mt < 4; mt++)
      af[mt] = *(const short8*)(&As[wm * 64 + mt * 16 + l15][quad * 8]);
#pragma unroll
    for (int ft = 0; ft < 4; ft++)
      bfr[ft] = *(const short8*)(&Bs[wf * 64 + ft * 16 + l15][quad * 8]);
#pragma unroll
    for (int mt = 0; mt < 4; mt++)
#pragma unroll
      for (int ft = 0; ft < 4; ft++)
        acc[mt][ft] = __builtin_amdgcn_mfma_f32_16x16x32_bf16(
            af[mt], bfr[ft], acc[mt][ft], 0, 0, 0);
  }

  if constexpr (MODE == 0) {
    ushort_t* C = (ushort_t*)Cv;
#pragma unroll
    for (int mt = 0; mt < 4; mt++)
#pragma unroll
      for (int ft = 0; ft < 4; ft++) {
        long col = f0 + wf * 64 + ft * 16 + l15;
#pragma unroll
        for (int r = 0; r < 4; r++) {
          long row = m0 + wm * 64 + mt * 16 + quad * 4 + r;
          C[row * F + col] = f2b(acc[mt][ft][r]);
        }
      }
  } else if constexpr (MODE == 1) {
    ushort_t* C = (ushort_t*)Cv;
    bool isk = (m0 < 512);
#pragma unroll
    for (int mt = 0; mt < 4; mt++)
#pragma unroll
      for (int ft = 0; ft < 4; ft++) {
        long col = f0 + wf * 64 + ft * 16 + l15;
#pragma unroll
        for (int r = 0; r < 4; r++) {
          long row = m0 + wm * 64 + mt * 16 + quad * 4 + r;
          float v = acc[mt][ft][r];
          if (isk) v = __expf(v);
          C[row * F + col] = f2b(v);
        }
      }
  } else {
    float* C = (float*)Cv;
    int b = (int)(m0 >> 12);
    float mu = murs[b * 2], rs = murs[b * 2 + 1];
#pragma unroll
    for (int mt = 0; mt < 4; mt++)
#pragma unroll
      for (int ft = 0; ft < 4; ft++) {
        long col = f0 + wf * 64 + ft * 16 + l15;
        float c1 = bias2[col] - rs * mu * gw1[col];
#pragma unroll
        for (int r = 0; r < 4; r++) {
          long row = m0 + wm * 64 + mt * 16 + quad * 4 + r;
          C[row * F + col] = rs * acc[mt][ft][r] + c1;
        }
      }
  }
}

// ---------------------------------------------------------------------------
// ctx partials via MFMA. kvT rows 0..511 = exp(k), 512..1023 = v.
// Grid (64 bh, 16 chunks of 256 n). NON-ATOMIC partial write:
//   ctxP[(cy*64+bh)*4096 + e*64 + d], ksumP[(cy*64+bh)*64 + d] (ones-MFMA).
// ---------------------------------------------------------------------------
__global__ __launch_bounds__(256) void ctx_mfma(
    const ushort_t* __restrict__ kvT, float* __restrict__ ctxP,
    float* __restrict__ ksumP) {
  int bh = blockIdx.x, cy = blockIdx.y;
  int b = bh >> 3, h = bh & 7;
  int tid = threadIdx.x, wv = tid >> 6, lane = tid & 63;
  int l15 = lane & 15, quad = lane >> 4;
  __shared__ __align__(16) ushort_t kTs[64 * 128];
  __shared__ __align__(16) ushort_t vTs[64 * 128];
  const ushort_t* kbase = kvT + (long)(h * 64) * 32768 + b * 4096 + cy * 256;
  const ushort_t* vbase = kbase + (long)512 * 32768;

  floatx4 acc[4], acc1;
  floatx4 zero = {0.f, 0.f, 0.f, 0.f};
  for (int i = 0; i < 4; i++) acc[i] = zero;
  acc1 = zero;
  short8 ones;
#pragma unroll
  for (int u = 0; u < 8; ++u) ones[u] = (short)0x3F80;  // bf16 1.0

  int r4 = lane >> 4, c = lane & 15;
  for (int tile = 0; tile < 2; ++tile) {
    __syncthreads();
#pragma unroll
    for (int i = 0; i < 4; ++i) {
      int row = wv * 16 + i * 4 + r4;
      int gc = (c & 8) | ((c ^ row) & 7);
      load_lds16(kbase + (long)row * 32768 + tile * 128 + gc * 8,
                 kTs + (wv * 16 + i * 4) * 128 + lane * 8);
      load_lds16(vbase + (long)row * 32768 + tile * 128 + gc * 8,
                 vTs + (wv * 16 + i * 4) * 128 + lane * 8);
    }
    __syncthreads();
#pragma unroll
    for (int ks = 0; ks < 4; ++ks) {
      int d = wv * 16 + l15;
      int cidx = ks * 4 + quad;
      int sa = (cidx & 8) | ((cidx ^ d) & 7);
      short8 a = *(const short8*)(kTs + d * 128 + sa * 8);
      short8 bf[4];
#pragma unroll
      for (int ft = 0; ft < 4; ++ft) {
        int e = ft * 16 + l15;
        int sb = (cidx & 8) | ((cidx ^ e) & 7);
        bf[ft] = *(const short8*)(vTs + e * 128 + sb * 8);
      }
#pragma unroll
      for (int ft = 0; ft < 4; ++ft)
        acc[ft] = __builtin_amdgcn_mfma_f32_16x16x32_bf16(a, bf[ft], acc[ft],
                                                          0, 0, 0);
      acc1 = __builtin_amdgcn_mfma_f32_16x16x32_bf16(a, ones, acc1, 0, 0, 0);
    }
  }
  float* cb = ctxP + ((long)cy * 64 + bh) * 4096;
#pragma unroll
  for (int ft = 0; ft < 4; ++ft)
#pragma unroll
    for (int r = 0; r < 4; ++r)
      cb[(ft * 16 + l15) * 64 + wv * 16 + quad * 4 + r] = acc[ft][r];
  if (l15 == 0) {
    float* kb = ksumP + ((long)cy * 64 + bh) * 64;
#pragma unroll
    for (int r = 0; r < 4; ++r) kb[wv * 16 + quad * 4 + r] = acc1[r];
  }
}

// ---------------------------------------------------------------------------
// Fold 16 chunk-partials and bake qp's B operand:
// ctxB[bh][e*64 + slot*8 + u] = bf16( (sum_c ctxP) * kinv[d] ),
//   d = chunk*8+u, slot = chunk ^ (e&7)  (MFMA-swizzled bf16 layout).
// kinv[d] = 1 / sum_c ksumP. Grid 1024 x 256 (16 blocks per bh).
// ---------------------------------------------------------------------------
__global__ __launch_bounds__(256) void reduce_kernel(
    const float* __restrict__ ctxP, const float* __restrict__ ksumP,
    ushort_t* __restrict__ ctxB) {
  int bid = blockIdx.x;
  int bh = bid >> 4;
  int j = (bid & 15) * 256 + threadIdx.x;  // 0..4095 within bh
  int e = j >> 6, d = j & 63;
  float ks = 0.f;
#pragma unroll
  for (int c = 0; c < 16; ++c) ks += ksumP[((long)c * 64 + bh) * 64 + d];
  float s = 0.f;
#pragma unroll
  for (int c = 0; c < 16; ++c) s += ctxP[((long)c * 64 + bh) * 4096 + j];
  int slot = (d >> 3) ^ (e & 7);
  ctxB[(long)bh * 4096 + e * 64 + slot * 8 + (d & 7)] = f2b(s / ks);
}

// ---------------------------------------------------------------------------
// Fused q-softmax + P@ctx MFMA. Grid (64 bh, 32 chunks of 128 tokens).
// q-tile via global_load_lds into XOR-swizzled LDS; ctxB pre-baked bf16;
// per-thread exp (thread pair owns one token); MFMA on raw exp; epilogue
// row-scale 0.125/s_n. Writes A2 (bf16) + GN stats atomics.
// ---------------------------------------------------------------------------
__global__ __launch_bounds__(256) void qp_gemm_kernel(
    const ushort_t* __restrict__ q, const ushort_t* __restrict__ ctxB,
    ushort_t* __restrict__ A2, float* __restrict__ gstats) {
  int bh = blockIdx.x, chunk = blockIdx.y;
  int b = bh >> 3, h = bh & 7;
  int tid = threadIdx.x, wv = tid >> 6, lane = tid & 63;
  int l15 = lane & 15, quad = lane >> 4;
  __shared__ __align__(16) ushort_t As[128 * 64];  // swizzled 128B rows
  __shared__ __align__(16) ushort_t Bs[64 * 64];   // swizzled (baked)
  __shared__ float rs[128];
  __shared__ float red[4][2];

  long rowbase = (long)b * 4096 + chunk * 128;

  // stage q-tile (128 tok x 64 d), swizzled chunks; wave wv -> 32 tokens
  {
    int tl = lane >> 3;  // token-in-group 0..7
    int c = lane & 7;    // dest chunk slot
    int j = c ^ tl;      // source chunk (row&7 == tl)
    const ushort_t* g = q + (rowbase + wv * 32 + tl) * 512 + h * 64 + j * 8;
#pragma unroll
    for (int i = 0; i < 4; ++i)
      load_lds16(g + (long)i * 8 * 512, As + (wv * 32 + i * 8) * 64 + lane * 8);
  }
  // stage ctxB (4096 ushorts, linear copy; swizzle pre-baked)
  {
#pragma unroll
    for (int i = 0; i < 2; ++i)
      load_lds16(ctxB + (long)bh * 4096 + (wv * 2 + i) * 512 + lane * 8,
                 Bs + (wv * 2 + i) * 512 + lane * 8);
  }
  __syncthreads();

  // per-thread exp + sum: threads (2t, 2t+1) own token t (4 slots each)
  {
    int t = tid >> 1, half = tid & 1;
    ushort_t* row = As + t * 64;
    float s = 0.f;
#pragma unroll
    for (int i = 0; i < 4; ++i) {
      int slot = half * 4 + ((i + t) & 3);  // rotate to spread banks
      short8 vq = *(const short8*)(row + slot * 8);
      short8 eo;
#pragma unroll
      for (int u = 0; u < 8; ++u) {
        float e = __expf(b2f((ushort_t)vq[u]));
        s += e;
        eo[u] = (short)f2b(e);
      }
      *(short8*)(row + slot * 8) = eo;
    }
    s += __shfl_xor(s, 1);
    if (half == 0) rs[t] = 0.125f / s;
  }
  __syncthreads();

  // MFMA: wave wv -> tokens wv*32..+31 x e 0..63 (2x4 of 16x16, K=64)
  floatx4 acc[2][4];
  floatx4 zero = {0.f, 0.f, 0.f, 0.f};
  for (int i = 0; i < 2; i++)
    for (int j = 0; j < 4; j++) acc[i][j] = zero;
#pragma unroll
  for (int k0 = 0; k0 < 2; ++k0) {
    short8 af[2], bfr[4];
#pragma unroll
    for (int mt = 0; mt < 2; mt++) {
      int row = wv * 32 + mt * 16 + l15;
      int slot = (k0 * 4 + quad) ^ (row & 7);
      af[mt] = *(const short8*)(As + row * 64 + slot * 8);
    }
#pragma unroll
    for (int ft = 0; ft < 4; ft++) {
      int e = ft * 16 + l15;
      int slot = (k0 * 4 + quad) ^ (e & 7);
      bfr[ft] = *(const short8*)(Bs + e * 64 + slot * 8);
    }
#pragma unroll
    for (int mt = 0; mt < 2; mt++)
#pragma unroll
      for (int ft = 0; ft < 4; ft++)
        acc[mt][ft] = __builtin_amdgcn_mfma_f32_16x16x32_bf16(
            af[mt], bfr[ft], acc[mt][ft], 0, 0, 0);
  }

  // epilogue: row-scale by rs, bf16 store, GN stats
  float lsum = 0.f, lss = 0.f;
#pragma unroll
  for (int mt = 0; mt < 2; mt++) {
    float rsv[4];
#pragma unroll
    for (int r = 0; r < 4; r++)
      rsv[r] = rs[wv * 32 + mt * 16 + quad * 4 + r];
#pragma unroll
    for (int ft = 0; ft < 4; ft++) {
      int col = h * 64 + ft * 16 + l15;
#pragma unroll
      for (int r = 0; r < 4; r++) {
        long row = rowbase + wv * 32 + mt * 16 + quad * 4 + r;
        float v = acc[mt][ft][r] * rsv[r];
        A2[row * 512 + col] = f2b(v);
        lsum += v;
        lss += v * v;
      }
    }
  }
  for (int o = 32; o > 0; o >>= 1) {
    lsum += __shfl_xor(lsum, o);
    lss += __shfl_xor(lss, o);
  }
  if (lane == 0) {
    red[wv][0] = lsum;
    red[wv][1] = lss;
  }
  __syncthreads();
  if (tid == 0) {
    float a = 0.f, c = 0.f;
    for (int w2 = 0; w2 < 4; w2++) {
      a += red[w2][0];
      c += red[w2][1];
    }
    atomicAdd(&gstats[b * 2], a);
    atomicAdd(&gstats[b * 2 + 1], c);
  }
}

// ---------------------------------------------------------------------------
__global__ __launch_bounds__(64) void finalize_murs(
    const float* __restrict__ gstats, float* __restrict__ murs) {
  int tid = threadIdx.x;
  if (tid < 8) {
    float cnt = 4096.f * 512.f;
    float mu = gstats[tid * 2] / cnt;
    float var = gstats[tid * 2 + 1] / cnt - mu * mu;
    murs[tid * 2] = mu;
    murs[tid * 2 + 1] = rsqrtf(var + 1e-5f);
  }
}

// ---------------------------------------------------------------------------
extern "C" void kernel_launch(void* const* d_in, const int* in_sizes, int n_in,
                              void* d_out, int out_size, void* d_ws,
                              size_t ws_size, hipStream_t stream) {
  const float* x = (const float*)d_in[0];
  const float* w_qkv = (const float*)d_in[1];
  const float* gn_scale = (const float*)d_in[2];
  const float* gn_bias = (const float*)d_in[3];
  const float* w_out = (const float*)d_in[4];
  const float* b_out = (const float*)d_in[5];
  float* out = (float*)d_out;

  char* w = (char*)d_ws;
  ushort_t* q = (ushort_t*)(w + 0);              // 33554432 B (32768x512 bf16)
  ushort_t* kvT = (ushort_t*)(w + 33554432);     // 67108864 B (1024x32768 bf16)
  ushort_t* A2 = (ushort_t*)(w + 100663296);     // 33554432 B (32768x512 bf16)
  float* ctxP = (float*)(w + 134217728);         // 16777216 B (16*64*4096 f32)
  float* ksumP = (float*)(w + 150994944);        // 262144 B (16*64*64 f32)
  ushort_t* xb = (ushort_t*)(w + 167772160);     // 16777216 B (32768x256 bf16)
  ushort_t* wqkvT = (ushort_t*)(w + 184549376);  // 786432 B (1536x256 bf16)
  ushort_t* w2T = (ushort_t*)(w + 185335808);    // 262144 B (256x512 bf16)
  ushort_t* ctxB = (ushort_t*)(w + 185630720);   // 524288 B (64x4096 bf16)
  float* gstats = (float*)(w + 186679296);       // 64 B
  float* murs = (float*)(w + 186695744);         // 64 B
  float* bias2 = (float*)(w + 186695808);        // 1024 B
  float* gw1 = (float*)(w + 186696832);          // 1024 B

  hipMemsetAsync(gstats, 0, 64, stream);

  cast_f32_bf16<<<8388608 / 4 / 256, 256, 0, stream>>>(x, xb);
  transpose_f32_bf16<<<dim3(1536 / 32, 256 / 32), 256, 0, stream>>>(
      w_qkv, wqkvT, 256, 1536, nullptr);
  transpose_f32_bf16<<<dim3(256 / 32, 512 / 32), 256, 0, stream>>>(
      w_out, w2T, 512, 256, gn_scale);
  prep_gw_kernel<<<4, 64, 0, stream>>>(gn_scale, gn_bias, w_out, b_out, gw1,
                                       bias2);
  // q GEMM: (32768x256)@(256x512) -> q[token][512] bf16
  gemm_tpl<0, false><<<dim3(256, 4), 256, 0, stream>>>(
      xb, wqkvT, q, 32768, 256, 512, nullptr, nullptr, nullptr);
  // kv GEMM transposed: (1024x256)@(256x32768) -> kvT[feat][token], exp(k).
  // SWAP grid: x = token tiles (Bt streamed once -> L3), y = feat tiles.
  gemm_tpl<1, true><<<dim3(256, 8), 256, 0, stream>>>(
      wqkvT + 512 * 256, xb, kvT, 1024, 256, 32768, nullptr, nullptr, nullptr);
  // context partials: pure MFMA + ksum via ones-MFMA (non-atomic)
  ctx_mfma<<<dim3(64, 16), 256, 0, stream>>>(kvT, ctxP, ksumP);
  // fold partials -> ctxB (kinv-scaled, bf16, pre-swizzled)
  reduce_kernel<<<1024, 256, 0, stream>>>(ctxP, ksumP, ctxB);
  // fused q-softmax + P@ctx -> A2 (bf16) + GN stats
  qp_gemm_kernel<<<dim3(64, 32), 256, 0, stream>>>(q, ctxB, A2, gstats);
  finalize_murs<<<1, 64, 0, stream>>>(gstats, murs);
  // final GEMM with folded GN epilogue: (32768x512)@(512x256) -> fp32 out
  gemm_tpl<2, false><<<dim3(256, 2), 256, 0, stream>>>(
      A2, w2T, out, 32768, 512, 256, murs, gw1, bias2);
}

// Round 9
// 239.299 us; speedup vs baseline: 1.1305x; 1.1305x over previous
//
#include <hip/hip_runtime.h>

// LinearAttention (fp32 in/out, bf16 internal MFMA):
// x(8,64,64,256) f32, w_qkv(256,1536) f32, gn_scale/bias(512) f32,
// w_out(512,256) f32, b_out(256) f32 -> out(8,64,64,256) f32
// B=8, N=4096 tokens/batch, HEADS=8, DH=64, HID=512, DIM=256.
//
// Softmaxes WITHOUT max subtraction (|q|,|k| <~ 6, exp fp32-safe).
// kvT[feat][32768] produced by operand-swapped GEMM, k rows store exp().
// ctx partials non-atomic; reduce folds partials + bakes kinv/bf16/swizzle
// into ctxB. qattn_kernel FUSES q-GEMM + q-softmax + P@ctx: exp in-register,
// row-sums via shfl butterfly, P via LDS C->A-layout round trip, per-lane
// row scale 0.125/s. GN folded into final GEMM.

typedef unsigned short ushort_t;
typedef __attribute__((ext_vector_type(8))) short short8;
typedef __attribute__((ext_vector_type(4))) float floatx4;

__device__ __forceinline__ float b2f(ushort_t u) {
  unsigned int i = ((unsigned int)u) << 16;
  float f;
  __builtin_memcpy(&f, &i, 4);
  return f;
}
__device__ __forceinline__ ushort_t f2b(float f) {
  unsigned int i;
  __builtin_memcpy(&i, &f, 4);
  unsigned int r = (i + 0x7FFFu + ((i >> 16) & 1u)) >> 16;
  return (ushort_t)r;
}

// async 16B global->LDS copy (HW dest = wave-uniform base + lane*16)
__device__ __forceinline__ void load_lds16(const ushort_t* g, ushort_t* l) {
  __builtin_amdgcn_global_load_lds(
      (const __attribute__((address_space(1))) unsigned int*)g,
      (__attribute__((address_space(3))) unsigned int*)l, 16, 0, 0);
}

// ---------------------------------------------------------------------------
__global__ __launch_bounds__(256) void cast_f32_bf16(
    const float* __restrict__ in, ushort_t* __restrict__ out) {
  long i = ((long)blockIdx.x * 256 + threadIdx.x) * 4;
  float4 v = *(const float4*)(in + i);
  ushort4 o;
  o.x = f2b(v.x);
  o.y = f2b(v.y);
  o.z = f2b(v.z);
  o.w = f2b(v.w);
  *(ushort4*)(out + i) = o;
}

// ---------------------------------------------------------------------------
__global__ __launch_bounds__(256) void transpose_f32_bf16(
    const float* __restrict__ in, ushort_t* __restrict__ out, int R, int C,
    const float* __restrict__ scale) {
  __shared__ ushort_t t[32][33];
  int c0 = blockIdx.x * 32, r0 = blockIdx.y * 32;
  int tx = threadIdx.x & 31, ty = threadIdx.x >> 5;
  for (int i = 0; i < 32; i += 8) {
    float s = scale ? scale[r0 + ty + i] : 1.0f;
    t[ty + i][tx] = f2b(in[(long)(r0 + ty + i) * C + c0 + tx] * s);
  }
  __syncthreads();
  for (int i = 0; i < 32; i += 8)
    out[(long)(c0 + ty + i) * R + r0 + tx] = t[tx][ty + i];
}

// ---------------------------------------------------------------------------
__global__ __launch_bounds__(64) void prep_gw_kernel(
    const float* __restrict__ gn_scale, const float* __restrict__ gn_bias,
    const float* __restrict__ w_out, const float* __restrict__ b_out,
    float* __restrict__ gw1, float* __restrict__ bias2) {
  int c = blockIdx.x * 64 + threadIdx.x;
  float g1 = 0.f, b2 = 0.f;
  for (int f = 0; f < 512; ++f) {
    float w = w_out[f * 256 + c];
    g1 += gn_scale[f] * w;
    b2 += gn_bias[f] * w;
  }
  gw1[c] = g1;
  bias2[c] = b2 + b_out[c];
}

// ---------------------------------------------------------------------------
// MFMA GEMM: C[M,F] = A[M,K] @ Bt[F,K]^T  (bf16 in, fp32 acc)
// MODE 1: bf16 out, rows<512 store exp(acc).  MODE 2: fp32 out + folded GN.
// SWAP: blockIdx.x indexes F so one x-round streams Bt once (L3-friendly).
// ---------------------------------------------------------------------------
template <int MODE, bool SWAP>
__global__ __launch_bounds__(256) void gemm_tpl(
    const ushort_t* __restrict__ A, const ushort_t* __restrict__ Bt,
    void* __restrict__ Cv, int M, int K, int F,
    const float* __restrict__ murs, const float* __restrict__ gw1,
    const float* __restrict__ bias2) {
  __shared__ __align__(16) ushort_t As[128][32];
  __shared__ __align__(16) ushort_t Bs[128][32];
  int tid = threadIdx.x;
  long m0 = (long)(SWAP ? blockIdx.y : blockIdx.x) * 128;
  long f0 = (long)(SWAP ? blockIdx.x : blockIdx.y) * 128;
  int wv = tid >> 6, lane = tid & 63;
  int wm = wv & 1, wf = wv >> 1;
  int l15 = lane & 15, quad = lane >> 4;

  floatx4 acc[4][4];
  floatx4 zero = {0.f, 0.f, 0.f, 0.f};
  for (int i = 0; i < 4; i++)
    for (int j = 0; j < 4; j++) acc[i][j] = zero;

  for (int k0 = 0; k0 < K; k0 += 32) {
    __syncthreads();
#pragma unroll
    for (int r = 0; r < 2; ++r) {
      int chunk = r * 256 + tid;
      int row = chunk >> 2;
      int kc = chunk & 3;
      load_lds16(A + (m0 + row) * (long)K + k0 + kc * 8, &As[row][kc * 8]);
      load_lds16(Bt + (f0 + row) * (long)K + k0 + kc * 8, &Bs[row][kc * 8]);
    }
    __syncthreads();
    short8 af[4], bfr[4];
#pragma unroll
    for (int mt = 0; mt < 4; mt++)
      af[mt] = *(const short8*)(&As[wm * 64 + mt * 16 + l15][quad * 8]);
#pragma unroll
    for (int ft = 0; ft < 4; ft++)
      bfr[ft] = *(const short8*)(&Bs[wf * 64 + ft * 16 + l15][quad * 8]);
#pragma unroll
    for (int mt = 0; mt < 4; mt++)
#pragma unroll
      for (int ft = 0; ft < 4; ft++)
        acc[mt][ft] = __builtin_amdgcn_mfma_f32_16x16x32_bf16(
            af[mt], bfr[ft], acc[mt][ft], 0, 0, 0);
  }

  if constexpr (MODE == 1) {
    ushort_t* C = (ushort_t*)Cv;
    bool isk = (m0 < 512);
#pragma unroll
    for (int mt = 0; mt < 4; mt++)
#pragma unroll
      for (int ft = 0; ft < 4; ft++) {
        long col = f0 + wf * 64 + ft * 16 + l15;
#pragma unroll
        for (int r = 0; r < 4; r++) {
          long row = m0 + wm * 64 + mt * 16 + quad * 4 + r;
          float v = acc[mt][ft][r];
          if (isk) v = __expf(v);
          C[row * F + col] = f2b(v);
        }
      }
  } else {
    float* C = (float*)Cv;
    int b = (int)(m0 >> 12);
    float mu = murs[b * 2], rs = murs[b * 2 + 1];
#pragma unroll
    for (int mt = 0; mt < 4; mt++)
#pragma unroll
      for (int ft = 0; ft < 4; ft++) {
        long col = f0 + wf * 64 + ft * 16 + l15;
        float c1 = bias2[col] - rs * mu * gw1[col];
#pragma unroll
        for (int r = 0; r < 4; r++) {
          long row = m0 + wm * 64 + mt * 16 + quad * 4 + r;
          C[row * F + col] = rs * acc[mt][ft][r] + c1;
        }
      }
  }
}

// ---------------------------------------------------------------------------
// ctx partials via MFMA. kvT rows 0..511 = exp(k), 512..1023 = v.
// Grid (64 bh, 16 chunks of 256 n). NON-ATOMIC partial writes.
// ---------------------------------------------------------------------------
__global__ __launch_bounds__(256) void ctx_mfma(
    const ushort_t* __restrict__ kvT, float* __restrict__ ctxP,
    float* __restrict__ ksumP) {
  int bh = blockIdx.x, cy = blockIdx.y;
  int b = bh >> 3, h = bh & 7;
  int tid = threadIdx.x, wv = tid >> 6, lane = tid & 63;
  int l15 = lane & 15, quad = lane >> 4;
  __shared__ __align__(16) ushort_t kTs[64 * 128];
  __shared__ __align__(16) ushort_t vTs[64 * 128];
  const ushort_t* kbase = kvT + (long)(h * 64) * 32768 + b * 4096 + cy * 256;
  const ushort_t* vbase = kbase + (long)512 * 32768;

  floatx4 acc[4], acc1;
  floatx4 zero = {0.f, 0.f, 0.f, 0.f};
  for (int i = 0; i < 4; i++) acc[i] = zero;
  acc1 = zero;
  short8 ones;
#pragma unroll
  for (int u = 0; u < 8; ++u) ones[u] = (short)0x3F80;  // bf16 1.0

  int r4 = lane >> 4, c = lane & 15;
  for (int tile = 0; tile < 2; ++tile) {
    __syncthreads();
#pragma unroll
    for (int i = 0; i < 4; ++i) {
      int row = wv * 16 + i * 4 + r4;
      int gc = (c & 8) | ((c ^ row) & 7);
      load_lds16(kbase + (long)row * 32768 + tile * 128 + gc * 8,
                 kTs + (wv * 16 + i * 4) * 128 + lane * 8);
      load_lds16(vbase + (long)row * 32768 + tile * 128 + gc * 8,
                 vTs + (wv * 16 + i * 4) * 128 + lane * 8);
    }
    __syncthreads();
#pragma unroll
    for (int ks = 0; ks < 4; ++ks) {
      int d = wv * 16 + l15;
      int cidx = ks * 4 + quad;
      int sa = (cidx & 8) | ((cidx ^ d) & 7);
      short8 a = *(const short8*)(kTs + d * 128 + sa * 8);
      short8 bf[4];
#pragma unroll
      for (int ft = 0; ft < 4; ++ft) {
        int e = ft * 16 + l15;
        int sb = (cidx & 8) | ((cidx ^ e) & 7);
        bf[ft] = *(const short8*)(vTs + e * 128 + sb * 8);
      }
#pragma unroll
      for (int ft = 0; ft < 4; ++ft)
        acc[ft] = __builtin_amdgcn_mfma_f32_16x16x32_bf16(a, bf[ft], acc[ft],
                                                          0, 0, 0);
      acc1 = __builtin_amdgcn_mfma_f32_16x16x32_bf16(a, ones, acc1, 0, 0, 0);
    }
  }
  float* cb = ctxP + ((long)cy * 64 + bh) * 4096;
#pragma unroll
  for (int ft = 0; ft < 4; ++ft)
#pragma unroll
    for (int r = 0; r < 4; ++r)
      cb[(ft * 16 + l15) * 64 + wv * 16 + quad * 4 + r] = acc[ft][r];
  if (l15 == 0) {
    float* kb = ksumP + ((long)cy * 64 + bh) * 64;
#pragma unroll
    for (int r = 0; r < 4; ++r) kb[wv * 16 + quad * 4 + r] = acc1[r];
  }
}

// ---------------------------------------------------------------------------
// Fold 16 chunk-partials and bake qattn's B operand:
// ctxB[bh][e*64 + slot*8 + u] = bf16( (sum_c ctxP) * kinv[d] ),
//   d = chunk*8+u, slot = chunk ^ (e&7)  (MFMA-swizzled bf16 layout).
// ---------------------------------------------------------------------------
__global__ __launch_bounds__(256) void reduce_kernel(
    const float* __restrict__ ctxP, const float* __restrict__ ksumP,
    ushort_t* __restrict__ ctxB) {
  int bid = blockIdx.x;
  int bh = bid >> 4;
  int j = (bid & 15) * 256 + threadIdx.x;  // 0..4095 within bh
  int e = j >> 6, d = j & 63;
  float ks = 0.f;
#pragma unroll
  for (int c = 0; c < 16; ++c) ks += ksumP[((long)c * 64 + bh) * 64 + d];
  float s = 0.f;
#pragma unroll
  for (int c = 0; c < 16; ++c) s += ctxP[((long)c * 64 + bh) * 4096 + j];
  int slot = (d >> 3) ^ (e & 7);
  ctxB[(long)bh * 4096 + e * 64 + slot * 8 + (d & 7)] = f2b(s / ks);
}

// ---------------------------------------------------------------------------
// FUSED q-GEMM + q-softmax + P@ctx. Grid (256 token-tiles, 4 col-tiles).
// Block 128 tok x 128 cols (2 heads); wave (wm,wf) = 64 tok x head (by*2+wf).
// K-loop computes q-tile; epilogue: exp in-register, row-sums via shfl
// butterfly over l15, P -> LDS (swizzled A-layout), stage ctxB (2 heads),
// P@ctx MFMA (K=64), scale 0.125/s (per-lane regs), store A2 + GN stats.
// ---------------------------------------------------------------------------
__global__ __launch_bounds__(256) void qattn_kernel(
    const ushort_t* __restrict__ xb, const ushort_t* __restrict__ wqT,
    const ushort_t* __restrict__ ctxB, ushort_t* __restrict__ A2,
    float* __restrict__ gstats) {
  __shared__ __align__(16) char lds[49216];
  ushort_t* As = (ushort_t*)lds;            // 128x32 (staging)
  ushort_t* Bs = (ushort_t*)(lds + 8192);   // 128x32 (staging)
  ushort_t* P = (ushort_t*)lds;             // [2][128][64] (epilogue, union)
  ushort_t* Cs = (ushort_t*)(lds + 32768);  // [2][4096]
  float* red = (float*)(lds + 49152);       // [8]

  int tid = threadIdx.x;
  int bx = blockIdx.x, by = blockIdx.y;
  long m0 = (long)bx * 128;
  long f0 = (long)by * 128;
  int wv = tid >> 6, lane = tid & 63;
  int wm = wv & 1, wf = wv >> 1;
  int l15 = lane & 15, quad = lane >> 4;
  int b = bx >> 5;  // 32 tiles of 128 tokens per batch

  floatx4 acc[4][4];
  floatx4 zero = {0.f, 0.f, 0.f, 0.f};
  for (int i = 0; i < 4; i++)
    for (int j = 0; j < 4; j++) acc[i][j] = zero;

  for (int k0 = 0; k0 < 256; k0 += 32) {
    __syncthreads();
#pragma unroll
    for (int r = 0; r < 2; ++r) {
      int chunk = r * 256 + tid;
      int row = chunk >> 2;
      int kc = chunk & 3;
      load_lds16(xb + (m0 + row) * 256 + k0 + kc * 8, As + row * 32 + kc * 8);
      load_lds16(wqT + (f0 + row) * 256 + k0 + kc * 8, Bs + row * 32 + kc * 8);
    }
    __syncthreads();
    short8 af[4], bfr[4];
#pragma unroll
    for (int mt = 0; mt < 4; mt++)
      af[mt] = *(const short8*)(As + (wm * 64 + mt * 16 + l15) * 32 + quad * 8);
#pragma unroll
    for (int ft = 0; ft < 4; ft++)
      bfr[ft] =
          *(const short8*)(Bs + (wf * 64 + ft * 16 + l15) * 32 + quad * 8);
#pragma unroll
    for (int mt = 0; mt < 4; mt++)
#pragma unroll
      for (int ft = 0; ft < 4; ft++)
        acc[mt][ft] = __builtin_amdgcn_mfma_f32_16x16x32_bf16(
            af[mt], bfr[ft], acc[mt][ft], 0, 0, 0);
  }
  __syncthreads();  // staging region dead; safe to reuse as P

  // async-stage ctxB for this block's two heads (16KB linear)
  {
    const ushort_t* cg = ctxB + ((long)(b * 8 + by * 2)) * 4096;
#pragma unroll
    for (int i = 0; i < 4; ++i)
      load_lds16(cg + (i * 4 + wv) * 512 + lane * 8,
                 Cs + (i * 4 + wv) * 512 + lane * 8);
  }

  // exp in-register + row sums (butterfly over l15) -> rs = 0.125/s
  float rs[4][4];
#pragma unroll
  for (int mt = 0; mt < 4; mt++)
#pragma unroll
    for (int r = 0; r < 4; r++) rs[mt][r] = 0.f;
#pragma unroll
  for (int mt = 0; mt < 4; mt++)
#pragma unroll
    for (int ft = 0; ft < 4; ft++)
#pragma unroll
      for (int r = 0; r < 4; r++) {
        float e = __expf(acc[mt][ft][r]);
        acc[mt][ft][r] = e;
        rs[mt][r] += e;
      }
#pragma unroll
  for (int mt = 0; mt < 4; mt++)
#pragma unroll
    for (int r = 0; r < 4; r++) {
      float t = rs[mt][r];
      t += __shfl_xor(t, 1);
      t += __shfl_xor(t, 2);
      t += __shfl_xor(t, 4);
      t += __shfl_xor(t, 8);
      rs[mt][r] = 0.125f / t;
    }

  // write P to LDS in swizzled A-layout (token rows, 16B-chunk swizzle)
  {
    ushort_t* Pw = P + wf * 8192;
#pragma unroll
    for (int mt = 0; mt < 4; mt++)
#pragma unroll
      for (int ft = 0; ft < 4; ft++) {
        int d = ft * 16 + l15;
#pragma unroll
        for (int r = 0; r < 4; r++) {
          int row = wm * 64 + mt * 16 + quad * 4 + r;
          int slot = (d >> 3) ^ (row & 7);
          Pw[row * 64 + slot * 8 + (d & 7)] = f2b(acc[mt][ft][r]);
        }
      }
  }
  __syncthreads();  // P + Cs visible

  // P@ctx MFMA: K=64
  floatx4 o[4][4];
  for (int i = 0; i < 4; i++)
    for (int j = 0; j < 4; j++) o[i][j] = zero;
  {
    const ushort_t* Pr = P + wf * 8192;
    const ushort_t* Cr = Cs + wf * 4096;
#pragma unroll
    for (int k0 = 0; k0 < 2; ++k0) {
      short8 af[4], bfr[4];
#pragma unroll
      for (int mt = 0; mt < 4; mt++) {
        int row = wm * 64 + mt * 16 + l15;
        int slot = (k0 * 4 + quad) ^ (row & 7);
        af[mt] = *(const short8*)(Pr + row * 64 + slot * 8);
      }
#pragma unroll
      for (int ft = 0; ft < 4; ft++) {
        int e = ft * 16 + l15;
        int slot = (k0 * 4 + quad) ^ (e & 7);
        bfr[ft] = *(const short8*)(Cr + e * 64 + slot * 8);
      }
#pragma unroll
      for (int mt = 0; mt < 4; mt++)
#pragma unroll
        for (int ft = 0; ft < 4; ft++)
          o[mt][ft] = __builtin_amdgcn_mfma_f32_16x16x32_bf16(af[mt], bfr[ft],
                                                              o[mt][ft], 0, 0,
                                                              0);
    }
  }

  // epilogue: row-scale (per-lane regs), store A2, GN stats
  float lsum = 0.f, lss = 0.f;
#pragma unroll
  for (int mt = 0; mt < 4; mt++)
#pragma unroll
    for (int ft = 0; ft < 4; ft++) {
      long col = f0 + wf * 64 + ft * 16 + l15;
#pragma unroll
      for (int r = 0; r < 4; r++) {
        long row = m0 + wm * 64 + mt * 16 + quad * 4 + r;
        float v = o[mt][ft][r] * rs[mt][r];
        A2[row * 512 + col] = f2b(v);
        lsum += v;
        lss += v * v;
      }
    }
  for (int s = 32; s > 0; s >>= 1) {
    lsum += __shfl_xor(lsum, s);
    lss += __shfl_xor(lss, s);
  }
  if (lane == 0) {
    red[wv * 2] = lsum;
    red[wv * 2 + 1] = lss;
  }
  __syncthreads();
  if (tid == 0) {
    float a = 0.f, c = 0.f;
    for (int w2 = 0; w2 < 4; w2++) {
      a += red[w2 * 2];
      c += red[w2 * 2 + 1];
    }
    atomicAdd(&gstats[b * 2], a);
    atomicAdd(&gstats[b * 2 + 1], c);
  }
}

// ---------------------------------------------------------------------------
__global__ __launch_bounds__(64) void finalize_murs(
    const float* __restrict__ gstats, float* __restrict__ murs) {
  int tid = threadIdx.x;
  if (tid < 8) {
    float cnt = 4096.f * 512.f;
    float mu = gstats[tid * 2] / cnt;
    float var = gstats[tid * 2 + 1] / cnt - mu * mu;
    murs[tid * 2] = mu;
    murs[tid * 2 + 1] = rsqrtf(var + 1e-5f);
  }
}

// ---------------------------------------------------------------------------
extern "C" void kernel_launch(void* const* d_in, const int* in_sizes, int n_in,
                              void* d_out, int out_size, void* d_ws,
                              size_t ws_size, hipStream_t stream) {
  const float* x = (const float*)d_in[0];
  const float* w_qkv = (const float*)d_in[1];
  const float* gn_scale = (const float*)d_in[2];
  const float* gn_bias = (const float*)d_in[3];
  const float* w_out = (const float*)d_in[4];
  const float* b_out = (const float*)d_in[5];
  float* out = (float*)d_out;

  char* w = (char*)d_ws;
  ushort_t* kvT = (ushort_t*)(w + 33554432);     // 67108864 B (1024x32768 bf16)
  ushort_t* A2 = (ushort_t*)(w + 100663296);     // 33554432 B (32768x512 bf16)
  float* ctxP = (float*)(w + 134217728);         // 16777216 B (16*64*4096 f32)
  float* ksumP = (float*)(w + 150994944);        // 262144 B (16*64*64 f32)
  ushort_t* xb = (ushort_t*)(w + 167772160);     // 16777216 B (32768x256 bf16)
  ushort_t* wqkvT = (ushort_t*)(w + 184549376);  // 786432 B (1536x256 bf16)
  ushort_t* w2T = (ushort_t*)(w + 185335808);    // 262144 B (256x512 bf16)
  ushort_t* ctxB = (ushort_t*)(w + 185630720);   // 524288 B (64x4096 bf16)
  float* gstats = (float*)(w + 186679296);       // 64 B
  float* murs = (float*)(w + 186695744);         // 64 B
  float* bias2 = (float*)(w + 186695808);        // 1024 B
  float* gw1 = (float*)(w + 186696832);          // 1024 B

  hipMemsetAsync(gstats, 0, 64, stream);

  cast_f32_bf16<<<8388608 / 4 / 256, 256, 0, stream>>>(x, xb);
  transpose_f32_bf16<<<dim3(1536 / 32, 256 / 32), 256, 0, stream>>>(
      w_qkv, wqkvT, 256, 1536, nullptr);
  transpose_f32_bf16<<<dim3(256 / 32, 512 / 32), 256, 0, stream>>>(
      w_out, w2T, 512, 256, gn_scale);
  prep_gw_kernel<<<4, 64, 0, stream>>>(gn_scale, gn_bias, w_out, b_out, gw1,
                                       bias2);
  // kv GEMM transposed: (1024x256)@(256x32768) -> kvT[feat][token], exp(k).
  gemm_tpl<1, true><<<dim3(256, 8), 256, 0, stream>>>(
      wqkvT + 512 * 256, xb, kvT, 1024, 256, 32768, nullptr, nullptr, nullptr);
  // context partials: pure MFMA + ksum via ones-MFMA (non-atomic)
  ctx_mfma<<<dim3(64, 16), 256, 0, stream>>>(kvT, ctxP, ksumP);
  // fold partials -> ctxB (kinv-scaled, bf16, pre-swizzled)
  reduce_kernel<<<1024, 256, 0, stream>>>(ctxP, ksumP, ctxB);
  // fused q-GEMM + softmax + P@ctx -> A2 (bf16) + GN stats
  qattn_kernel<<<dim3(256, 4), 256, 0, stream>>>(xb, wqkvT, ctxB, A2, gstats);
  finalize_murs<<<1, 64, 0, stream>>>(gstats, murs);
  // final GEMM with folded GN epilogue: (32768x512)@(512x256) -> fp32 out
  gemm_tpl<2, false><<<dim3(256, 2), 256, 0, stream>>>(
      A2, w2T, out, 32768, 512, 256, murs, gw1, bias2);
}